// Round 12
// baseline (553.956 us; speedup 1.0000x reference)
//
#include <hip/hip_runtime.h>
#include <hip/hip_bf16.h>

// MEASUREMENT ROUND: R5 structure (pure kernels) with idempotent x8 repeat
// loops in every kernel so each rises above the 39us harness poison-fills in
// rocprof's top-5 -> per-kernel breakdown. Output identical (all repeats
// write the same values). real_dur ~= shown_dur / 8.

#define N 4096
#define D 64
#define H 4
#define HD 256
#define TS 66
#define RCHUNK 16
#define RJ (N / RCHUNK)
#define REP 8

__device__ __forceinline__ void fma4(float4& a, float s, const float4& b) {
  a.x = fmaf(s, b.x, a.x); a.y = fmaf(s, b.y, a.y);
  a.z = fmaf(s, b.z, a.z); a.w = fmaf(s, b.w, a.w);
}

// ---------- proj body ----------
__device__ __forceinline__ void proj_body(const float (*xs)[64], int r0,
    const float* __restrict__ W, const float* __restrict__ asrc,
    const float* __restrict__ adst, float* __restrict__ h2,
    float* __restrict__ ssrc, float* __restrict__ sdst) {
  int tid = threadIdx.x;
  int lane6 = tid & 63;
  int c0 = lane6 * 4;
  int hh = lane6 >> 4;
  int rbase = (tid >> 6) * 2;
  float4 acc0 = make_float4(0.f, 0.f, 0.f, 0.f);
  float4 acc1 = make_float4(0.f, 0.f, 0.f, 0.f);
#pragma unroll
  for (int kq = 0; kq < 16; ++kq) {
    const float* Wk = W + kq * 4 * 256 + c0;
    float4 w0 = *(const float4*)(Wk);
    float4 w1 = *(const float4*)(Wk + 256);
    float4 w2 = *(const float4*)(Wk + 512);
    float4 w3 = *(const float4*)(Wk + 768);
    float4 x0 = *(const float4*)(&xs[rbase][kq * 4]);
    float4 x1 = *(const float4*)(&xs[rbase + 1][kq * 4]);
    fma4(acc0, x0.x, w0); fma4(acc0, x0.y, w1); fma4(acc0, x0.z, w2); fma4(acc0, x0.w, w3);
    fma4(acc1, x1.x, w0); fma4(acc1, x1.y, w1); fma4(acc1, x1.z, w2); fma4(acc1, x1.w, w3);
  }
  float4 av = *(const float4*)(asrc + c0);
  float4 bv = *(const float4*)(adst + c0);
#pragma unroll
  for (int r = 0; r < 2; ++r) {
    float4 a = (r == 0) ? acc0 : acc1;
    int row = r0 + rbase + r;
    *(float4*)(h2 + row * 256 + c0) = a;
    float ps = a.x * av.x + a.y * av.y + a.z * av.z + a.w * av.w;
    float pd = a.x * bv.x + a.y * bv.y + a.z * bv.z + a.w * bv.w;
#pragma unroll
    for (int off = 8; off > 0; off >>= 1) {
      ps += __shfl_down(ps, off);
      pd += __shfl_down(pd, off);
    }
    if ((lane6 & 15) == 0) {
      ssrc[hh * N + row] = ps;
      sdst[hh * N + row] = pd;
    }
  }
}

// ---------- layer1: encoder + proj ----------
__global__ __launch_bounds__(256) void k_encproj(const float* __restrict__ x,
    const float* __restrict__ Wenc, const float* __restrict__ benc,
    const float* __restrict__ W, const float* __restrict__ asrc,
    const float* __restrict__ adst, float* __restrict__ h2,
    float* __restrict__ ssrc, float* __restrict__ sdst) {
  __shared__ float xs[8][64];
  int tid = threadIdx.x;
  int r0 = blockIdx.x * 8;
#pragma unroll 1
  for (int rep = 0; rep < REP; ++rep) {
    __syncthreads();
    {
      int row = tid >> 5, c = (tid & 31) * 2;
      const float* xr = x + (r0 + row) * 64;
      float a0 = benc[c], a1 = benc[c + 1];
#pragma unroll
      for (int k = 0; k < 64; ++k) {
        float xv = xr[k];
        float2 w = *(const float2*)(Wenc + k * 64 + c);
        a0 = fmaf(xv, w.x, a0);
        a1 = fmaf(xv, w.y, a1);
      }
      xs[row][c] = fmaxf(a0, 0.f);
      xs[row][c + 1] = fmaxf(a1, 0.f);
    }
    __syncthreads();
    proj_body(xs, r0, W, asrc, adst, h2, ssrc, sdst);
  }
}

// ---------- layer2 proj ----------
__global__ __launch_bounds__(256) void k_proj(const float* __restrict__ hin,
    const float* __restrict__ W, const float* __restrict__ asrc,
    const float* __restrict__ adst, float* __restrict__ h2,
    float* __restrict__ ssrc, float* __restrict__ sdst) {
  __shared__ float xs[8][64];
  int tid = threadIdx.x;
  int r0 = blockIdx.x * 8;
#pragma unroll 1
  for (int rep = 0; rep < REP; ++rep) {
    __syncthreads();
    if (tid < 128) ((float4*)xs)[tid] = ((const float4*)(hin + r0 * 64))[tid];
    __syncthreads();
    proj_body(xs, r0, W, asrc, adst, h2, ssrc, sdst);
  }
}

// ---------- rank stage 1 ----------
__global__ __launch_bounds__(256) void k_rank_part(const float* __restrict__ ssrc,
                                                   int* __restrict__ partial) {
  __shared__ __align__(16) float vs[RJ];
  int h = blockIdx.x >> 4, bi = blockIdx.x & 15;
  int c = blockIdx.y;
  int tid = threadIdx.x;
#pragma unroll 1
  for (int rep = 0; rep < REP; ++rep) {
    __syncthreads();
    vs[tid] = ssrc[h * N + c * RJ + tid];
    __syncthreads();
    int i = bi * 256 + tid;
    float vi = ssrc[h * N + i];
    int jbase = c * RJ;
    int rank = 0;
    const float4* vs4 = (const float4*)vs;
#pragma unroll 4
    for (int j4 = 0; j4 < RJ / 4; ++j4) {
      float4 q = vs4[j4];
      int jb = jbase + (j4 << 2);
      rank += (q.x < vi || (q.x == vi && jb < i));
      rank += (q.y < vi || (q.y == vi && jb + 1 < i));
      rank += (q.z < vi || (q.z == vi && jb + 2 < i));
      rank += (q.w < vi || (q.w == vi && jb + 3 < i));
    }
    partial[(c * H + h) * N + i] = rank;
  }
}

// ---------- rank stage 2 ----------
__global__ __launch_bounds__(256) void k_rank_reduce(const float* __restrict__ ssrc,
                                                     const int* __restrict__ partial,
                                                     float* __restrict__ srtv,
                                                     int* __restrict__ srti) {
  int h = blockIdx.x >> 4, bi = blockIdx.x & 15;
  int i = bi * 256 + threadIdx.x;
#pragma unroll 1
  for (int rep = 0; rep < REP; ++rep) {
    int rank = 0;
#pragma unroll
    for (int c = 0; c < RCHUNK; ++c) rank += partial[(c * H + h) * N + i];
    srtv[h * N + rank] = ssrc[h * N + i];
    srti[h * N + rank] = i;
  }
}

// ---------- S1 ----------
__global__ __launch_bounds__(128) void k_s1(const float* __restrict__ h2,
                                            const int* __restrict__ srti,
                                            const float* __restrict__ srtv,
                                            float* __restrict__ wA, float* __restrict__ wB,
                                            float* __restrict__ TA, float* __restrict__ TB) {
  int h = blockIdx.x >> 6, c = blockIdx.x & 63, col = threadIdx.x;
  __shared__ int pj[64];
  __shared__ float wa[64], wb[64];
  int j0 = c * 64;
#pragma unroll 1
  for (int rep = 0; rep < REP; ++rep) {
    __syncthreads();
    float m1 = srtv[h * N + N - 1];
    if (col < 64) {
      int j = j0 + col;
      pj[col] = srti[h * N + j];
      float sv = srtv[h * N + j];
      float a = expf(sv - m1);
      float b = expf(0.2f * (sv - m1));
      wa[col] = a; wb[col] = b;
      wA[h * N + j] = a; wB[h * N + j] = b;
    }
    __syncthreads();
    if (col < 65) {
      float accA = 0.f, accB = 0.f;
#pragma unroll 8
      for (int j = 0; j < 64; ++j) {
        float val = (col < 64) ? h2[pj[j] * HD + h * 64 + col] : 1.0f;
        accA = fmaf(wa[j], val, accA);
        accB = fmaf(wb[j], val, accB);
      }
      TA[(h * 64 + c) * TS + col] = accA;
      TB[(h * 64 + c) * TS + col] = accB;
    }
  }
}

// ---------- S3 ----------
__global__ __launch_bounds__(128) void k_s3(const float* __restrict__ h2,
                                            const int* __restrict__ srti,
                                            const float* __restrict__ wA, const float* __restrict__ wB,
                                            const float* __restrict__ TA, const float* __restrict__ TB,
                                            float* __restrict__ SA, float* __restrict__ PB) {
  int h = blockIdx.x >> 6, c = blockIdx.x & 63, col = threadIdx.x;
  __shared__ int pj[64];
  __shared__ float wa[64], wb[64];
  int j0 = c * 64;
#pragma unroll 1
  for (int rep = 0; rep < REP; ++rep) {
    __syncthreads();
    if (col < 64) {
      pj[col] = srti[h * N + j0 + col];
      wa[col] = wA[h * N + j0 + col];
      wb[col] = wB[h * N + j0 + col];
    }
    __syncthreads();
    if (col < 65) {
      float offA = 0.f, offB = 0.f;
      for (int cc = c + 1; cc < 64; ++cc) offA += TA[(h * 64 + cc) * TS + col];
      for (int cc = 0; cc < c; ++cc)      offB += TB[(h * 64 + cc) * TS + col];
      float v[64];
#pragma unroll
      for (int j = 0; j < 64; ++j)
        v[j] = (col < 64) ? h2[pj[j] * HD + h * 64 + col] : 1.0f;
      float acc = offA;
#pragma unroll
      for (int j = 63; j >= 0; --j) {
        acc = fmaf(wa[j], v[j], acc);
        SA[(size_t)(h * (N + 1) + j0 + j) * TS + col] = acc;
      }
      acc = offB;
#pragma unroll
      for (int j = 0; j < 64; ++j) {
        acc = fmaf(wb[j], v[j], acc);
        PB[(size_t)(h * (N + 1) + j0 + j + 1) * TS + col] = acc;
      }
      if (c == 63) SA[(size_t)(h * (N + 1) + N) * TS + col] = 0.f;
      if (c == 0)  PB[(size_t)(h * (N + 1) + 0) * TS + col] = 0.f;
    }
  }
}

// ---------- target ----------
template <int MODE>
__global__ __launch_bounds__(256) void k_target_t(const float* __restrict__ sdst,
                                                  const float* __restrict__ srtv,
                                                  const float* __restrict__ SA,
                                                  const float* __restrict__ PB,
                                                  const float* __restrict__ bias,
                                                  float* __restrict__ hout,
                                                  const float* __restrict__ Wact,
                                                  const float* __restrict__ bact,
                                                  const float* __restrict__ Wcri,
                                                  const float* __restrict__ bcri,
                                                  float* __restrict__ out) {
  __shared__ float bnd[4][64];
  int tid = threadIdx.x;
  int t = blockIdx.x * 4 + (tid >> 6);
  int lane = tid & 63;
#pragma unroll 1
  for (int rep = 0; rep < REP; ++rep) {
    __syncthreads();
    { int hh = tid >> 6, l = tid & 63; bnd[hh][l] = srtv[hh * N + l * 64]; }
    __syncthreads();
    float acc = 0.f;
#pragma unroll
    for (int h = 0; h < H; ++h) {
      const float* sv = srtv + h * N;
      float dst = sdst[h * N + t];
      float thr = -dst;
      float m1 = sv[N - 1];
      unsigned long long b1 = __ballot(bnd[h][lane] <= thr);
      int c1 = __popcll(b1);
      int seg = c1 > 0 ? c1 - 1 : 0;
      unsigned long long b2 = __ballot(sv[seg * 64 + lane] <= thr);
      int k = seg * 64 + __popcll(b2);
      float u = dst + m1;
      float g = fmaxf(u, 0.2f * u);
      float wAt = expf(u - g);
      float wBt = expf(0.2f * u - g);
      const float* sa = SA + (size_t)(h * (N + 1) + k) * TS;
      const float* pb = PB + (size_t)(h * (N + 1) + k) * TS;
      float num = wAt * sa[lane] + wBt * pb[lane];
      float den = wAt * sa[64] + wBt * pb[64];
      acc += num / den;
    }
    float hv = fmaxf(acc * 0.25f + bias[lane], 0.f);
    if constexpr (MODE == 0) {
      hout[t * 64 + lane] = hv;
    } else {
      float p0 = hv * Wact[lane * 2 + 0];
      float p1 = hv * Wact[lane * 2 + 1];
      float p2 = hv * Wcri[lane];
#pragma unroll
      for (int off = 32; off > 0; off >>= 1) {
        p0 += __shfl_down(p0, off);
        p1 += __shfl_down(p1, off);
        p2 += __shfl_down(p2, off);
      }
      if (lane == 0) {
        float l0 = fminf(fmaxf(p0 + bact[0], -5.f), 5.f);
        float l1 = fminf(fmaxf(p1 + bact[1], -5.f), 5.f);
        out[t * 2 + 0] = l0;
        out[t * 2 + 1] = fabsf(l1);
        out[2 * N + t] = p2 + bcri[0];
      }
    }
  }
}

extern "C" void kernel_launch(void* const* d_in, const int* in_sizes, int n_in,
                              void* d_out, int out_size, void* d_ws, size_t ws_size,
                              hipStream_t stream) {
    (void)in_sizes; (void)n_in; (void)out_size; (void)ws_size;
    const float* x     = (const float*)d_in[0];
    const float* W_enc = (const float*)d_in[1];
    const float* b_enc = (const float*)d_in[2];
    const float* W1    = (const float*)d_in[3];
    const float* as1   = (const float*)d_in[4];
    const float* ad1   = (const float*)d_in[5];
    const float* b1    = (const float*)d_in[6];
    const float* W2    = (const float*)d_in[7];
    const float* as2   = (const float*)d_in[8];
    const float* ad2   = (const float*)d_in[9];
    const float* b2    = (const float*)d_in[10];
    const float* W_act = (const float*)d_in[11];
    const float* b_act = (const float*)d_in[12];
    const float* W_cri = (const float*)d_in[13];
    const float* b_cri = (const float*)d_in[14];
    float* out = (float*)d_out;

    float* p = (float*)d_ws;
    float* h2   = p; p += N * HD;
    float* hA   = p; p += N * D;
    float* ssrc = p; p += H * N;
    float* sdst = p; p += H * N;
    float* srtv = p; p += H * N;
    int*   srti = (int*)p; p += H * N;
    float* wA   = p; p += H * N;
    float* wB   = p; p += H * N;
    float* TA   = p; p += H * 64 * TS;
    float* TB   = p; p += H * 64 * TS;
    float* SA   = p; p += (size_t)H * (N + 1) * TS;
    float* PB   = p; p += (size_t)H * (N + 1) * TS;
    int*   rpart = (int*)p; p += RCHUNK * H * N;

    dim3 rp_grid(H * 16, RCHUNK);

    // layer 1
    k_encproj<<<N / 8, 256, 0, stream>>>(x, W_enc, b_enc, W1, as1, ad1, h2, ssrc, sdst);
    k_rank_part<<<rp_grid, 256, 0, stream>>>(ssrc, rpart);
    k_rank_reduce<<<H * 16, 256, 0, stream>>>(ssrc, rpart, srtv, srti);
    k_s1<<<H * 64, 128, 0, stream>>>(h2, srti, srtv, wA, wB, TA, TB);
    k_s3<<<H * 64, 128, 0, stream>>>(h2, srti, wA, wB, TA, TB, SA, PB);
    k_target_t<0><<<N / 4, 256, 0, stream>>>(sdst, srtv, SA, PB, b1, hA,
                                             nullptr, nullptr, nullptr, nullptr, nullptr);

    // layer 2
    k_proj<<<N / 8, 256, 0, stream>>>(hA, W2, as2, ad2, h2, ssrc, sdst);
    k_rank_part<<<rp_grid, 256, 0, stream>>>(ssrc, rpart);
    k_rank_reduce<<<H * 16, 256, 0, stream>>>(ssrc, rpart, srtv, srti);
    k_s1<<<H * 64, 128, 0, stream>>>(h2, srti, srtv, wA, wB, TA, TB);
    k_s3<<<H * 64, 128, 0, stream>>>(h2, srti, wA, wB, TA, TB, SA, PB);
    k_target_t<1><<<N / 4, 256, 0, stream>>>(sdst, srtv, SA, PB, b2, nullptr,
                                             W_act, b_act, W_cri, b_cri, out);
}

// Round 13
// 146.805 us; speedup vs baseline: 3.7734x; 3.7734x over previous
//
#include <hip/hip_runtime.h>

// GAT on fully-connected graph, N=4096, F=D=64, H=4, OUT=2.
// 7 fence-free dispatches: encproj | rankF | s3off | targetproj | rankF |
// s3off | target2.  s3off builds CHUNK-LOCAL suffix/prefix tables (no cross-
// chunk offsets -> no s1, no spin); per-chunk totals go through IF$-coherent
// relaxed atomics and the LAST block per head builds the small SufT/PreT
// chunk-offset tables. Target adds SufT/PreT rows at read time.
// e[t,s,h]=lrelu(dst_t+src_s) factors per branch around -dst.

#define N 4096
#define D 64
#define H 4
#define HD 256
#define TS 66

#define AS(p, v) __hip_atomic_store((p), (v), __ATOMIC_RELAXED, __HIP_MEMORY_SCOPE_AGENT)
#define AL(p)    __hip_atomic_load((p), __ATOMIC_RELAXED, __HIP_MEMORY_SCOPE_AGENT)

__device__ __forceinline__ void fma4(float4& a, float s, const float4& b) {
  a.x = fmaf(s, b.x, a.x); a.y = fmaf(s, b.y, a.y);
  a.z = fmaf(s, b.z, a.z); a.w = fmaf(s, b.w, a.w);
}

// ---- proj: 8 rows from LDS xs, W from global; writes h2, ssrc, sdst ----
__device__ __forceinline__ void proj_dev(const float (*xs)[64], int r0,
    const float* __restrict__ W, const float* __restrict__ asrc,
    const float* __restrict__ adst, float* __restrict__ h2,
    float* __restrict__ ssrc, float* __restrict__ sdst) {
  int tid = threadIdx.x;
  int lane6 = tid & 63;
  int c0 = lane6 * 4;
  int hh = lane6 >> 4;
  int rbase = (tid >> 6) * 2;
  float4 acc0 = make_float4(0.f, 0.f, 0.f, 0.f);
  float4 acc1 = make_float4(0.f, 0.f, 0.f, 0.f);
#pragma unroll
  for (int kq = 0; kq < 16; ++kq) {
    const float* Wk = W + kq * 4 * 256 + c0;
    float4 w0 = *(const float4*)(Wk);
    float4 w1 = *(const float4*)(Wk + 256);
    float4 w2 = *(const float4*)(Wk + 512);
    float4 w3 = *(const float4*)(Wk + 768);
    float4 x0 = *(const float4*)(&xs[rbase][kq * 4]);
    float4 x1 = *(const float4*)(&xs[rbase + 1][kq * 4]);
    fma4(acc0, x0.x, w0); fma4(acc0, x0.y, w1); fma4(acc0, x0.z, w2); fma4(acc0, x0.w, w3);
    fma4(acc1, x1.x, w0); fma4(acc1, x1.y, w1); fma4(acc1, x1.z, w2); fma4(acc1, x1.w, w3);
  }
  float4 av = *(const float4*)(asrc + c0);
  float4 bv = *(const float4*)(adst + c0);
#pragma unroll
  for (int r = 0; r < 2; ++r) {
    float4 a = (r == 0) ? acc0 : acc1;
    int row = r0 + rbase + r;
    *(float4*)(h2 + row * 256 + c0) = a;
    float ps = a.x * av.x + a.y * av.y + a.z * av.z + a.w * av.w;
    float pd = a.x * bv.x + a.y * bv.y + a.z * bv.z + a.w * bv.w;
#pragma unroll
    for (int off = 8; off > 0; off >>= 1) {
      ps += __shfl_down(ps, off);
      pd += __shfl_down(pd, off);
    }
    if ((lane6 & 15) == 0) {
      ssrc[hh * N + row] = ps;
      sdst[hh * N + row] = pd;
    }
  }
}

// ---- layer1: encoder fused with proj; block 0 zeroes sync counters ----
__global__ __launch_bounds__(256) void k_encproj(const float* __restrict__ x,
    const float* __restrict__ Wenc, const float* __restrict__ benc,
    const float* __restrict__ W, const float* __restrict__ asrc,
    const float* __restrict__ adst, float* __restrict__ h2,
    float* __restrict__ ssrc, float* __restrict__ sdst,
    int* __restrict__ sync) {
  __shared__ float xs[8][64];
  int tid = threadIdx.x;
  int r0 = blockIdx.x * 8;
  if (blockIdx.x == 0 && tid < 136) sync[tid] = 0;
  {
    int row = tid >> 5, c = (tid & 31) * 2;
    const float* xr = x + (r0 + row) * 64;
    float a0 = benc[c], a1 = benc[c + 1];
#pragma unroll
    for (int k = 0; k < 64; ++k) {
      float xv = xr[k];
      float2 w = *(const float2*)(Wenc + k * 64 + c);
      a0 = fmaf(xv, w.x, a0);
      a1 = fmaf(xv, w.y, a1);
    }
    xs[row][c] = fmaxf(a0, 0.f);
    xs[row][c + 1] = fmaxf(a1, 0.f);
  }
  __syncthreads();
  proj_dev(xs, r0, W, asrc, adst, h2, ssrc, sdst);
}

// ---- rank fused: partial counts via IF$ atomics; last block reduces ----
__global__ __launch_bounds__(256) void k_rank_f(const float* __restrict__ ssrc,
    int* __restrict__ rpart, int* __restrict__ cnt,
    float* __restrict__ srtv, int* __restrict__ srti) {
  __shared__ __align__(16) float vs[256];
  __shared__ int lastflag;
  int h = blockIdx.x >> 4, ig = blockIdx.x & 15, c = blockIdx.y;
  int tid = threadIdx.x;
  vs[tid] = ssrc[h * N + c * 256 + tid];
  __syncthreads();
  int i = ig * 256 + tid;
  float vi = ssrc[h * N + i];
  int jbase = c * 256;
  int rank = 0;
  const float4* vs4 = (const float4*)vs;
#pragma unroll 4
  for (int j4 = 0; j4 < 64; ++j4) {
    float4 q = vs4[j4];
    int jb = jbase + (j4 << 2);
    rank += (q.x < vi || (q.x == vi && jb < i));
    rank += (q.y < vi || (q.y == vi && jb + 1 < i));
    rank += (q.z < vi || (q.z == vi && jb + 2 < i));
    rank += (q.w < vi || (q.w == vi && jb + 3 < i));
  }
  AS(&rpart[(c * H + h) * N + i], rank);
  asm volatile("s_waitcnt vmcnt(0)" ::: "memory");
  __syncthreads();
  if (tid == 0) {
    int prev = __hip_atomic_fetch_add(&cnt[h * 16 + ig], 1,
                 __ATOMIC_RELAXED, __HIP_MEMORY_SCOPE_AGENT);
    lastflag = (prev == 15);
  }
  __syncthreads();
  if (lastflag) {
    int rk = 0;
#pragma unroll
    for (int cc = 0; cc < 16; ++cc) rk += AL(&rpart[(cc * H + h) * N + i]);
    srtv[h * N + rk] = vi;
    srti[h * N + rk] = i;
  }
}

// ---- s3off: chunk-LOCAL suffix/prefix tables + totals; last block/head
//      builds SufT/PreT (65 rows of chunk-offsets) and zeroes row N. ----
// grid 256 (h*64+c), block 512 (8 waves, 8 rows each).
__global__ __launch_bounds__(512) void k_s3off(const float* __restrict__ h2,
    const int* __restrict__ srti, const float* __restrict__ srtv,
    float* __restrict__ TA, float* __restrict__ TB, int* __restrict__ cnt,
    float* __restrict__ SA, float* __restrict__ PB,
    float* __restrict__ SufT, float* __restrict__ PreT) {
  __shared__ int pj[64];
  __shared__ float wa[64], wb[64];
  __shared__ float vt[64][66];
  __shared__ float segA[8][66], segB[8][66];
  __shared__ int lastflag;
  int h = blockIdx.x >> 6, c = blockIdx.x & 63;
  int tid = threadIdx.x, w = tid >> 6, lane = tid & 63;
  int j0 = c * 64;
  if (tid < 64) {
    int j = j0 + tid;
    pj[tid] = srti[h * N + j];
    float sv = srtv[h * N + j];
    float m1 = srtv[h * N + N - 1];
    wa[tid] = expf(sv - m1);
    wb[tid] = expf(0.2f * (sv - m1));
  }
  __syncthreads();
  // gather 64 rows, 8 per wave
#pragma unroll
  for (int jj = 0; jj < 8; ++jj) {
    int j = jj * 8 + w;
    vt[j][lane] = h2[pj[j] * HD + h * 64 + lane];
  }
  __syncthreads();
  // per-wave segment sums over rows [w*8, w*8+8)
  {
    float sA = 0.f, sB = 0.f;
#pragma unroll
    for (int jj = 0; jj < 8; ++jj) {
      int j = w * 8 + jj;
      float v = vt[j][lane];
      sA = fmaf(wa[j], v, sA);
      sB = fmaf(wb[j], v, sB);
    }
    segA[w][lane] = sA; segB[w][lane] = sB;
    if (lane == 0) {
      float swA = 0.f, swB = 0.f;
#pragma unroll
      for (int jj = 0; jj < 8; ++jj) { swA += wa[w * 8 + jj]; swB += wb[w * 8 + jj]; }
      segA[w][64] = swA; segB[w][64] = swB;
    }
  }
  __syncthreads();
  size_t base = (size_t)h * (N + 1);
  // local suffix chain (cols 0..63)
  {
    float acc = 0.f;
    for (int w2 = w + 1; w2 < 8; ++w2) acc += segA[w2][lane];
#pragma unroll
    for (int jj = 7; jj >= 0; --jj) {
      int j = w * 8 + jj;
      acc = fmaf(wa[j], vt[j][lane], acc);
      SA[(base + j0 + j) * TS + lane] = acc;
    }
  }
  // local prefix chain (cols 0..63)
  {
    float acc = 0.f;
    for (int w2 = 0; w2 < w; ++w2) acc += segB[w2][lane];
#pragma unroll
    for (int jj = 0; jj < 8; ++jj) {
      int j = w * 8 + jj;
      PB[(base + j0 + j) * TS + lane] = acc;
      acc = fmaf(wb[j], vt[j][lane], acc);
    }
  }
  // col-64 (weight-sum) chains: lane0 -> SA, lane1 -> PB
  if (lane == 0) {
    float a = 0.f;
    for (int w2 = w + 1; w2 < 8; ++w2) a += segA[w2][64];
#pragma unroll
    for (int jj = 7; jj >= 0; --jj) {
      int j = w * 8 + jj;
      a += wa[j];
      SA[(base + j0 + j) * TS + 64] = a;
    }
  }
  if (lane == 1) {
    float bsum = 0.f;
    for (int w2 = 0; w2 < w; ++w2) bsum += segB[w2][64];
#pragma unroll
    for (int jj = 0; jj < 8; ++jj) {
      int j = w * 8 + jj;
      PB[(base + j0 + j) * TS + 64] = bsum;
      bsum += wb[j];
    }
  }
  // publish chunk totals (IF$-coherent)
  if (tid < 65) {
    float tA = 0.f, tB = 0.f;
#pragma unroll
    for (int w2 = 0; w2 < 8; ++w2) { tA += segA[w2][tid]; tB += segB[w2][tid]; }
    AS(&TA[(h * 64 + c) * TS + tid], tA);
    AS(&TB[(h * 64 + c) * TS + tid], tB);
  }
  asm volatile("s_waitcnt vmcnt(0)" ::: "memory");
  __syncthreads();
  if (tid == 0) {
    int prev = __hip_atomic_fetch_add(&cnt[h], 1,
                 __ATOMIC_RELAXED, __HIP_MEMORY_SCOPE_AGENT);
    lastflag = (prev == 63);
  }
  __syncthreads();
  if (lastflag && tid < 65) {
    float acc = 0.f;
    SufT[(h * 65 + 64) * TS + tid] = 0.f;
    for (int cc = 63; cc >= 0; --cc) {
      SufT[(h * 65 + cc) * TS + tid] = acc;        // sum_{c'>cc}
      acc += AL(&TA[(h * 64 + cc) * TS + tid]);
    }
    acc = 0.f;
    for (int cc = 0; cc < 64; ++cc) {
      PreT[(h * 65 + cc) * TS + tid] = acc;        // sum_{c'<cc}
      acc += AL(&TB[(h * 64 + cc) * TS + tid]);
    }
    PreT[(h * 65 + 64) * TS + tid] = acc;
    SA[(base + N) * TS + tid] = 0.f;
    PB[(base + N) * TS + tid] = 0.f;
  }
}

// ---- target core: rows t0 + tid>>6 + 4*task; local tables + Suf/Pre ----
template <int MODE>
__device__ __forceinline__ void target_dev(int t0, int tid,
    const float* __restrict__ sdst, const float* __restrict__ srtv,
    const float* __restrict__ SA, const float* __restrict__ PB,
    const float* __restrict__ SufT, const float* __restrict__ PreT,
    const float* __restrict__ bias, float (*xsout)[64], const float (*bnd)[64],
    const float* __restrict__ Wact, const float* __restrict__ bact,
    const float* __restrict__ Wcri, const float* __restrict__ bcri,
    float* __restrict__ out, int ntask) {
  int lane = tid & 63;
  for (int task = 0; task < ntask; ++task) {
    int r = task * 4 + (tid >> 6);
    int t = t0 + r;
    float acc = 0.f;
#pragma unroll
    for (int h = 0; h < H; ++h) {
      const float* sv = srtv + h * N;
      float dst = sdst[h * N + t];
      float thr = -dst;
      float m1 = sv[N - 1];
      unsigned long long b1m = __ballot(bnd[h][lane] <= thr);
      int c1 = __popcll(b1m);
      int seg = c1 > 0 ? c1 - 1 : 0;
      unsigned long long b2m = __ballot(sv[seg * 64 + lane] <= thr);
      int k = seg * 64 + __popcll(b2m);
      int c = k >> 6;
      float u = dst + m1;
      float g = fmaxf(u, 0.2f * u);
      float wAt = expf(u - g);
      float wBt = expf(0.2f * u - g);
      const float* sa = SA + (size_t)(h * (N + 1) + k) * TS;
      const float* pb = PB + (size_t)(h * (N + 1) + k) * TS;
      const float* sf = SufT + (size_t)(h * 65 + c) * TS;
      const float* pr = PreT + (size_t)(h * 65 + c) * TS;
      float num = wAt * (sa[lane] + sf[lane]) + wBt * (pb[lane] + pr[lane]);
      float den = wAt * (sa[64] + sf[64]) + wBt * (pb[64] + pr[64]);
      acc += num / den;
    }
    float hv = fmaxf(acc * 0.25f + bias[lane], 0.f);
    if constexpr (MODE == 0) {
      xsout[r][lane] = hv;
    } else {
      float p0 = hv * Wact[lane * 2 + 0];
      float p1 = hv * Wact[lane * 2 + 1];
      float p2 = hv * Wcri[lane];
#pragma unroll
      for (int off = 32; off > 0; off >>= 1) {
        p0 += __shfl_down(p0, off);
        p1 += __shfl_down(p1, off);
        p2 += __shfl_down(p2, off);
      }
      if (lane == 0) {
        float l0 = fminf(fmaxf(p0 + bact[0], -5.f), 5.f);
        float l1 = fminf(fmaxf(p1 + bact[1], -5.f), 5.f);
        out[t * 2 + 0] = l0;
        out[t * 2 + 1] = fabsf(l1);
        out[2 * N + t] = p2 + bcri[0];
      }
    }
  }
}

// ---- target1 (8 rows -> LDS) fused with proj2 ----
__global__ __launch_bounds__(256) void k_targetproj(
    const float* __restrict__ sdst, const float* __restrict__ srtv,
    const float* __restrict__ SA, const float* __restrict__ PB,
    const float* __restrict__ SufT, const float* __restrict__ PreT,
    const float* __restrict__ bias,
    const float* __restrict__ W, const float* __restrict__ asrc,
    const float* __restrict__ adst, float* __restrict__ h2,
    float* __restrict__ ssrc2, float* __restrict__ sdst2) {
  __shared__ float xs[8][64];
  __shared__ float bnd[4][64];
  int tid = threadIdx.x;
  int r0 = blockIdx.x * 8;
  { int hh = tid >> 6, l = tid & 63; bnd[hh][l] = srtv[hh * N + l * 64]; }
  __syncthreads();
  target_dev<0>(r0, tid, sdst, srtv, SA, PB, SufT, PreT, bias, xs, bnd,
                nullptr, nullptr, nullptr, nullptr, nullptr, 2);
  __syncthreads();
  proj_dev(xs, r0, W, asrc, adst, h2, ssrc2, sdst2);
}

// ---- target2 + heads ----
__global__ __launch_bounds__(256) void k_target2(
    const float* __restrict__ sdst, const float* __restrict__ srtv,
    const float* __restrict__ SA, const float* __restrict__ PB,
    const float* __restrict__ SufT, const float* __restrict__ PreT,
    const float* __restrict__ bias,
    const float* __restrict__ Wact, const float* __restrict__ bact,
    const float* __restrict__ Wcri, const float* __restrict__ bcri,
    float* __restrict__ out) {
  __shared__ float bnd[4][64];
  int tid = threadIdx.x;
  { int hh = tid >> 6, l = tid & 63; bnd[hh][l] = srtv[hh * N + l * 64]; }
  __syncthreads();
  target_dev<1>(blockIdx.x * 4, tid, sdst, srtv, SA, PB, SufT, PreT, bias,
                nullptr, bnd, Wact, bact, Wcri, bcri, out, 1);
}

extern "C" void kernel_launch(void* const* d_in, const int* in_sizes, int n_in,
                              void* d_out, int out_size, void* d_ws, size_t ws_size,
                              hipStream_t stream) {
    (void)in_sizes; (void)n_in; (void)out_size; (void)ws_size;
    const float* x     = (const float*)d_in[0];
    const float* W_enc = (const float*)d_in[1];
    const float* b_enc = (const float*)d_in[2];
    const float* W1    = (const float*)d_in[3];
    const float* as1   = (const float*)d_in[4];
    const float* ad1   = (const float*)d_in[5];
    const float* b1    = (const float*)d_in[6];
    const float* W2    = (const float*)d_in[7];
    const float* as2   = (const float*)d_in[8];
    const float* ad2   = (const float*)d_in[9];
    const float* b2    = (const float*)d_in[10];
    const float* W_act = (const float*)d_in[11];
    const float* b_act = (const float*)d_in[12];
    const float* W_cri = (const float*)d_in[13];
    const float* b_cri = (const float*)d_in[14];
    float* out = (float*)d_out;

    float* p = (float*)d_ws;
    float* h2    = p; p += N * HD;
    float* ssrc1 = p; p += H * N;
    float* sdst1 = p; p += H * N;
    float* ssrc2 = p; p += H * N;
    float* sdst2 = p; p += H * N;
    float* srtv  = p; p += H * N;
    int*   srti  = (int*)p; p += H * N;
    float* TA    = p; p += H * 64 * TS;
    float* TB    = p; p += H * 64 * TS;
    float* SufT  = p; p += H * 65 * TS;
    float* PreT  = p; p += H * 65 * TS;
    float* SA    = p; p += (size_t)H * (N + 1) * TS;
    float* PB    = p; p += (size_t)H * (N + 1) * TS;
    int*   rpart = (int*)p; p += 16 * H * N;
    int*   sync  = (int*)p; p += 256;
    // [0:64) rank cnt1, [64:68) s3 cnt1, [68:132) rank cnt2, [132:136) s3 cnt2

    int* rcnt1 = sync;
    int* scnt1 = sync + 64;
    int* rcnt2 = sync + 68;
    int* scnt2 = sync + 132;

    dim3 rgrid(64, 16);

    // layer 1
    k_encproj<<<N / 8, 256, 0, stream>>>(x, W_enc, b_enc, W1, as1, ad1,
                                         h2, ssrc1, sdst1, sync);
    k_rank_f<<<rgrid, 256, 0, stream>>>(ssrc1, rpart, rcnt1, srtv, srti);
    k_s3off<<<256, 512, 0, stream>>>(h2, srti, srtv, TA, TB, scnt1, SA, PB, SufT, PreT);
    k_targetproj<<<N / 8, 256, 0, stream>>>(sdst1, srtv, SA, PB, SufT, PreT, b1,
                                            W2, as2, ad2, h2, ssrc2, sdst2);
    // layer 2
    k_rank_f<<<rgrid, 256, 0, stream>>>(ssrc2, rpart, rcnt2, srtv, srti);
    k_s3off<<<256, 512, 0, stream>>>(h2, srti, srtv, TA, TB, scnt2, SA, PB, SufT, PreT);
    k_target2<<<N / 4, 256, 0, stream>>>(sdst2, srtv, SA, PB, SufT, PreT, b2,
                                         W_act, b_act, W_cri, b_cri, out);
}

// Round 14
// 100.697 us; speedup vs baseline: 5.5012x; 1.4579x over previous
//
#include <hip/hip_runtime.h>

// GAT on fully-connected graph, N=4096, F=D=64, H=4, OUT=2.
// 7 fence-free dispatches: encproj | rankF | s3off | targetproj | rankF |
// s3off | target2.  s3off builds CHUNK-LOCAL suffix/prefix tables (no s1,
// no spin); per-chunk totals via IF$-coherent relaxed atomics; LAST block
// per head builds SufT/PreT chunk-offset tables with a PARALLEL LDS-staged
// scan (R13's serial tail was the 39us regression). Target adds SufT/PreT
// rows at read time. e[t,s,h]=lrelu(dst_t+src_s) factors per branch.

#define N 4096
#define D 64
#define H 4
#define HD 256
#define TS 66

#define AS(p, v) __hip_atomic_store((p), (v), __ATOMIC_RELAXED, __HIP_MEMORY_SCOPE_AGENT)
#define AL(p)    __hip_atomic_load((p), __ATOMIC_RELAXED, __HIP_MEMORY_SCOPE_AGENT)

__device__ __forceinline__ void fma4(float4& a, float s, const float4& b) {
  a.x = fmaf(s, b.x, a.x); a.y = fmaf(s, b.y, a.y);
  a.z = fmaf(s, b.z, a.z); a.w = fmaf(s, b.w, a.w);
}

// ---- proj: 8 rows from LDS xs, W from global; writes h2, ssrc, sdst ----
__device__ __forceinline__ void proj_dev(const float (*xs)[64], int r0,
    const float* __restrict__ W, const float* __restrict__ asrc,
    const float* __restrict__ adst, float* __restrict__ h2,
    float* __restrict__ ssrc, float* __restrict__ sdst) {
  int tid = threadIdx.x;
  int lane6 = tid & 63;
  int c0 = lane6 * 4;
  int hh = lane6 >> 4;
  int rbase = (tid >> 6) * 2;
  float4 acc0 = make_float4(0.f, 0.f, 0.f, 0.f);
  float4 acc1 = make_float4(0.f, 0.f, 0.f, 0.f);
#pragma unroll
  for (int kq = 0; kq < 16; ++kq) {
    const float* Wk = W + kq * 4 * 256 + c0;
    float4 w0 = *(const float4*)(Wk);
    float4 w1 = *(const float4*)(Wk + 256);
    float4 w2 = *(const float4*)(Wk + 512);
    float4 w3 = *(const float4*)(Wk + 768);
    float4 x0 = *(const float4*)(&xs[rbase][kq * 4]);
    float4 x1 = *(const float4*)(&xs[rbase + 1][kq * 4]);
    fma4(acc0, x0.x, w0); fma4(acc0, x0.y, w1); fma4(acc0, x0.z, w2); fma4(acc0, x0.w, w3);
    fma4(acc1, x1.x, w0); fma4(acc1, x1.y, w1); fma4(acc1, x1.z, w2); fma4(acc1, x1.w, w3);
  }
  float4 av = *(const float4*)(asrc + c0);
  float4 bv = *(const float4*)(adst + c0);
#pragma unroll
  for (int r = 0; r < 2; ++r) {
    float4 a = (r == 0) ? acc0 : acc1;
    int row = r0 + rbase + r;
    *(float4*)(h2 + row * 256 + c0) = a;
    float ps = a.x * av.x + a.y * av.y + a.z * av.z + a.w * av.w;
    float pd = a.x * bv.x + a.y * bv.y + a.z * bv.z + a.w * bv.w;
#pragma unroll
    for (int off = 8; off > 0; off >>= 1) {
      ps += __shfl_down(ps, off);
      pd += __shfl_down(pd, off);
    }
    if ((lane6 & 15) == 0) {
      ssrc[hh * N + row] = ps;
      sdst[hh * N + row] = pd;
    }
  }
}

// ---- layer1: encoder fused with proj; block 0 zeroes sync counters ----
__global__ __launch_bounds__(256) void k_encproj(const float* __restrict__ x,
    const float* __restrict__ Wenc, const float* __restrict__ benc,
    const float* __restrict__ W, const float* __restrict__ asrc,
    const float* __restrict__ adst, float* __restrict__ h2,
    float* __restrict__ ssrc, float* __restrict__ sdst,
    int* __restrict__ sync) {
  __shared__ float xs[8][64];
  int tid = threadIdx.x;
  int r0 = blockIdx.x * 8;
  if (blockIdx.x == 0 && tid < 136) sync[tid] = 0;
  {
    int row = tid >> 5, c = (tid & 31) * 2;
    const float* xr = x + (r0 + row) * 64;
    float a0 = benc[c], a1 = benc[c + 1];
#pragma unroll
    for (int k = 0; k < 64; ++k) {
      float xv = xr[k];
      float2 w = *(const float2*)(Wenc + k * 64 + c);
      a0 = fmaf(xv, w.x, a0);
      a1 = fmaf(xv, w.y, a1);
    }
    xs[row][c] = fmaxf(a0, 0.f);
    xs[row][c + 1] = fmaxf(a1, 0.f);
  }
  __syncthreads();
  proj_dev(xs, r0, W, asrc, adst, h2, ssrc, sdst);
}

// ---- rank fused: partial counts via IF$ atomics; last block reduces ----
__global__ __launch_bounds__(256) void k_rank_f(const float* __restrict__ ssrc,
    int* __restrict__ rpart, int* __restrict__ cnt,
    float* __restrict__ srtv, int* __restrict__ srti) {
  __shared__ __align__(16) float vs[256];
  __shared__ int lastflag;
  int h = blockIdx.x >> 4, ig = blockIdx.x & 15, c = blockIdx.y;
  int tid = threadIdx.x;
  vs[tid] = ssrc[h * N + c * 256 + tid];
  __syncthreads();
  int i = ig * 256 + tid;
  float vi = ssrc[h * N + i];
  int jbase = c * 256;
  int rank = 0;
  const float4* vs4 = (const float4*)vs;
#pragma unroll 4
  for (int j4 = 0; j4 < 64; ++j4) {
    float4 q = vs4[j4];
    int jb = jbase + (j4 << 2);
    rank += (q.x < vi || (q.x == vi && jb < i));
    rank += (q.y < vi || (q.y == vi && jb + 1 < i));
    rank += (q.z < vi || (q.z == vi && jb + 2 < i));
    rank += (q.w < vi || (q.w == vi && jb + 3 < i));
  }
  AS(&rpart[(c * H + h) * N + i], rank);
  asm volatile("s_waitcnt vmcnt(0)" ::: "memory");
  __syncthreads();
  if (tid == 0) {
    int prev = __hip_atomic_fetch_add(&cnt[h * 16 + ig], 1,
                 __ATOMIC_RELAXED, __HIP_MEMORY_SCOPE_AGENT);
    lastflag = (prev == 15);
  }
  __syncthreads();
  if (lastflag) {
    int rk = 0;
#pragma unroll
    for (int cc = 0; cc < 16; ++cc) rk += AL(&rpart[(cc * H + h) * N + i]);
    srtv[h * N + rk] = vi;
    srti[h * N + rk] = i;
  }
}

// ---- s3off: chunk-LOCAL suffix/prefix tables + totals; last block/head
//      builds SufT/PreT via PARALLEL LDS-staged scan. ----
// grid 256 (h*64+c), block 512 (8 waves, 8 rows each).
__global__ __launch_bounds__(512) void k_s3off(const float* __restrict__ h2,
    const int* __restrict__ srti, const float* __restrict__ srtv,
    float* __restrict__ TA, float* __restrict__ TB, int* __restrict__ cnt,
    float* __restrict__ SA, float* __restrict__ PB,
    float* __restrict__ SufT, float* __restrict__ PreT) {
  __shared__ int pj[64];
  __shared__ float wa[64], wb[64];
  __shared__ float vt[64][66];
  __shared__ float segA[8][66], segB[8][66];
  __shared__ int lastflag;
  int h = blockIdx.x >> 6, c = blockIdx.x & 63;
  int tid = threadIdx.x, w = tid >> 6, lane = tid & 63;
  int j0 = c * 64;
  if (tid < 64) {
    int j = j0 + tid;
    pj[tid] = srti[h * N + j];
    float sv = srtv[h * N + j];
    float m1 = srtv[h * N + N - 1];
    wa[tid] = expf(sv - m1);
    wb[tid] = expf(0.2f * (sv - m1));
  }
  __syncthreads();
  // gather 64 rows, 8 per wave
#pragma unroll
  for (int jj = 0; jj < 8; ++jj) {
    int j = jj * 8 + w;
    vt[j][lane] = h2[pj[j] * HD + h * 64 + lane];
  }
  __syncthreads();
  // per-wave segment sums over rows [w*8, w*8+8)
  {
    float sA = 0.f, sB = 0.f;
#pragma unroll
    for (int jj = 0; jj < 8; ++jj) {
      int j = w * 8 + jj;
      float v = vt[j][lane];
      sA = fmaf(wa[j], v, sA);
      sB = fmaf(wb[j], v, sB);
    }
    segA[w][lane] = sA; segB[w][lane] = sB;
    if (lane == 0) {
      float swA = 0.f, swB = 0.f;
#pragma unroll
      for (int jj = 0; jj < 8; ++jj) { swA += wa[w * 8 + jj]; swB += wb[w * 8 + jj]; }
      segA[w][64] = swA; segB[w][64] = swB;
    }
  }
  __syncthreads();
  size_t base = (size_t)h * (N + 1);
  // local suffix chain (cols 0..63)
  {
    float acc = 0.f;
    for (int w2 = w + 1; w2 < 8; ++w2) acc += segA[w2][lane];
#pragma unroll
    for (int jj = 7; jj >= 0; --jj) {
      int j = w * 8 + jj;
      acc = fmaf(wa[j], vt[j][lane], acc);
      SA[(base + j0 + j) * TS + lane] = acc;
    }
  }
  // local prefix chain (cols 0..63)
  {
    float acc = 0.f;
    for (int w2 = 0; w2 < w; ++w2) acc += segB[w2][lane];
#pragma unroll
    for (int jj = 0; jj < 8; ++jj) {
      int j = w * 8 + jj;
      PB[(base + j0 + j) * TS + lane] = acc;
      acc = fmaf(wb[j], vt[j][lane], acc);
    }
  }
  // col-64 (weight-sum) chains: lane0 -> SA, lane1 -> PB
  if (lane == 0) {
    float a = 0.f;
    for (int w2 = w + 1; w2 < 8; ++w2) a += segA[w2][64];
#pragma unroll
    for (int jj = 7; jj >= 0; --jj) {
      int j = w * 8 + jj;
      a += wa[j];
      SA[(base + j0 + j) * TS + 64] = a;
    }
  }
  if (lane == 1) {
    float bsum = 0.f;
    for (int w2 = 0; w2 < w; ++w2) bsum += segB[w2][64];
#pragma unroll
    for (int jj = 0; jj < 8; ++jj) {
      int j = w * 8 + jj;
      PB[(base + j0 + j) * TS + 64] = bsum;
      bsum += wb[j];
    }
  }
  // publish chunk totals (IF$-coherent)
  if (tid < 65) {
    float tA = 0.f, tB = 0.f;
#pragma unroll
    for (int w2 = 0; w2 < 8; ++w2) { tA += segA[w2][tid]; tB += segB[w2][tid]; }
    AS(&TA[(h * 64 + c) * TS + tid], tA);
    AS(&TB[(h * 64 + c) * TS + tid], tB);
  }
  asm volatile("s_waitcnt vmcnt(0)" ::: "memory");
  __syncthreads();
  if (tid == 0) {
    int prev = __hip_atomic_fetch_add(&cnt[h], 1,
                 __ATOMIC_RELAXED, __HIP_MEMORY_SCOPE_AGENT);
    lastflag = (prev == 63);
  }
  __syncthreads();
  if (!lastflag) return;
  // ---- PARALLEL SufT/PreT build: stage 64x65 totals in LDS, chain from LDS ----
  __syncthreads();
#pragma unroll
  for (int it = 0; it < 9; ++it) {
    int idx = it * 512 + tid;
    if (idx < 64 * 65) {
      int cc = idx / 65, col = idx - cc * 65;
      vt[cc][col] = AL(&TA[(h * 64 + cc) * TS + col]);
    }
  }
  __syncthreads();
  if (tid < 65) {
    float acc = 0.f;
    SufT[(h * 65 + 64) * TS + tid] = 0.f;
    for (int cc = 63; cc >= 0; --cc) {
      SufT[(h * 65 + cc) * TS + tid] = acc;        // sum_{c'>cc}
      acc += vt[cc][tid];
    }
  }
  __syncthreads();
#pragma unroll
  for (int it = 0; it < 9; ++it) {
    int idx = it * 512 + tid;
    if (idx < 64 * 65) {
      int cc = idx / 65, col = idx - cc * 65;
      vt[cc][col] = AL(&TB[(h * 64 + cc) * TS + col]);
    }
  }
  __syncthreads();
  if (tid < 65) {
    float acc = 0.f;
    for (int cc = 0; cc < 64; ++cc) {
      PreT[(h * 65 + cc) * TS + tid] = acc;        // sum_{c'<cc}
      acc += vt[cc][tid];
    }
    PreT[(h * 65 + 64) * TS + tid] = acc;
    SA[(base + N) * TS + tid] = 0.f;
    PB[(base + N) * TS + tid] = 0.f;
  }
}

// ---- target core: rows t0 + tid>>6 + 4*task; local tables + Suf/Pre ----
template <int MODE>
__device__ __forceinline__ void target_dev(int t0, int tid,
    const float* __restrict__ sdst, const float* __restrict__ srtv,
    const float* __restrict__ SA, const float* __restrict__ PB,
    const float* __restrict__ SufT, const float* __restrict__ PreT,
    const float* __restrict__ bias, float (*xsout)[64], const float (*bnd)[64],
    const float* __restrict__ Wact, const float* __restrict__ bact,
    const float* __restrict__ Wcri, const float* __restrict__ bcri,
    float* __restrict__ out, int ntask) {
  int lane = tid & 63;
  for (int task = 0; task < ntask; ++task) {
    int r = task * 4 + (tid >> 6);
    int t = t0 + r;
    float acc = 0.f;
#pragma unroll
    for (int h = 0; h < H; ++h) {
      const float* sv = srtv + h * N;
      float dst = sdst[h * N + t];
      float thr = -dst;
      float m1 = sv[N - 1];
      unsigned long long b1m = __ballot(bnd[h][lane] <= thr);
      int c1 = __popcll(b1m);
      int seg = c1 > 0 ? c1 - 1 : 0;
      unsigned long long b2m = __ballot(sv[seg * 64 + lane] <= thr);
      int k = seg * 64 + __popcll(b2m);
      int c = k >> 6;
      float u = dst + m1;
      float g = fmaxf(u, 0.2f * u);
      float wAt = expf(u - g);
      float wBt = expf(0.2f * u - g);
      const float* sa = SA + (size_t)(h * (N + 1) + k) * TS;
      const float* pb = PB + (size_t)(h * (N + 1) + k) * TS;
      const float* sf = SufT + (size_t)(h * 65 + c) * TS;
      const float* pr = PreT + (size_t)(h * 65 + c) * TS;
      float num = wAt * (sa[lane] + sf[lane]) + wBt * (pb[lane] + pr[lane]);
      float den = wAt * (sa[64] + sf[64]) + wBt * (pb[64] + pr[64]);
      acc += num / den;
    }
    float hv = fmaxf(acc * 0.25f + bias[lane], 0.f);
    if constexpr (MODE == 0) {
      xsout[r][lane] = hv;
    } else {
      float p0 = hv * Wact[lane * 2 + 0];
      float p1 = hv * Wact[lane * 2 + 1];
      float p2 = hv * Wcri[lane];
#pragma unroll
      for (int off = 32; off > 0; off >>= 1) {
        p0 += __shfl_down(p0, off);
        p1 += __shfl_down(p1, off);
        p2 += __shfl_down(p2, off);
      }
      if (lane == 0) {
        float l0 = fminf(fmaxf(p0 + bact[0], -5.f), 5.f);
        float l1 = fminf(fmaxf(p1 + bact[1], -5.f), 5.f);
        out[t * 2 + 0] = l0;
        out[t * 2 + 1] = fabsf(l1);
        out[2 * N + t] = p2 + bcri[0];
      }
    }
  }
}

// ---- target1 (8 rows -> LDS) fused with proj2 ----
__global__ __launch_bounds__(256) void k_targetproj(
    const float* __restrict__ sdst, const float* __restrict__ srtv,
    const float* __restrict__ SA, const float* __restrict__ PB,
    const float* __restrict__ SufT, const float* __restrict__ PreT,
    const float* __restrict__ bias,
    const float* __restrict__ W, const float* __restrict__ asrc,
    const float* __restrict__ adst, float* __restrict__ h2,
    float* __restrict__ ssrc2, float* __restrict__ sdst2) {
  __shared__ float xs[8][64];
  __shared__ float bnd[4][64];
  int tid = threadIdx.x;
  int r0 = blockIdx.x * 8;
  { int hh = tid >> 6, l = tid & 63; bnd[hh][l] = srtv[hh * N + l * 64]; }
  __syncthreads();
  target_dev<0>(r0, tid, sdst, srtv, SA, PB, SufT, PreT, bias, xs, bnd,
                nullptr, nullptr, nullptr, nullptr, nullptr, 2);
  __syncthreads();
  proj_dev(xs, r0, W, asrc, adst, h2, ssrc2, sdst2);
}

// ---- target2 + heads ----
__global__ __launch_bounds__(256) void k_target2(
    const float* __restrict__ sdst, const float* __restrict__ srtv,
    const float* __restrict__ SA, const float* __restrict__ PB,
    const float* __restrict__ SufT, const float* __restrict__ PreT,
    const float* __restrict__ bias,
    const float* __restrict__ Wact, const float* __restrict__ bact,
    const float* __restrict__ Wcri, const float* __restrict__ bcri,
    float* __restrict__ out) {
  __shared__ float bnd[4][64];
  int tid = threadIdx.x;
  { int hh = tid >> 6, l = tid & 63; bnd[hh][l] = srtv[hh * N + l * 64]; }
  __syncthreads();
  target_dev<1>(blockIdx.x * 4, tid, sdst, srtv, SA, PB, SufT, PreT, bias,
                nullptr, bnd, Wact, bact, Wcri, bcri, out, 1);
}

extern "C" void kernel_launch(void* const* d_in, const int* in_sizes, int n_in,
                              void* d_out, int out_size, void* d_ws, size_t ws_size,
                              hipStream_t stream) {
    (void)in_sizes; (void)n_in; (void)out_size; (void)ws_size;
    const float* x     = (const float*)d_in[0];
    const float* W_enc = (const float*)d_in[1];
    const float* b_enc = (const float*)d_in[2];
    const float* W1    = (const float*)d_in[3];
    const float* as1   = (const float*)d_in[4];
    const float* ad1   = (const float*)d_in[5];
    const float* b1    = (const float*)d_in[6];
    const float* W2    = (const float*)d_in[7];
    const float* as2   = (const float*)d_in[8];
    const float* ad2   = (const float*)d_in[9];
    const float* b2    = (const float*)d_in[10];
    const float* W_act = (const float*)d_in[11];
    const float* b_act = (const float*)d_in[12];
    const float* W_cri = (const float*)d_in[13];
    const float* b_cri = (const float*)d_in[14];
    float* out = (float*)d_out;

    float* p = (float*)d_ws;
    float* h2    = p; p += N * HD;
    float* ssrc1 = p; p += H * N;
    float* sdst1 = p; p += H * N;
    float* ssrc2 = p; p += H * N;
    float* sdst2 = p; p += H * N;
    float* srtv  = p; p += H * N;
    int*   srti  = (int*)p; p += H * N;
    float* TA    = p; p += H * 64 * TS;
    float* TB    = p; p += H * 64 * TS;
    float* SufT  = p; p += H * 65 * TS;
    float* PreT  = p; p += H * 65 * TS;
    float* SA    = p; p += (size_t)H * (N + 1) * TS;
    float* PB    = p; p += (size_t)H * (N + 1) * TS;
    int*   rpart = (int*)p; p += 16 * H * N;
    int*   sync  = (int*)p; p += 256;

    int* rcnt1 = sync;
    int* scnt1 = sync + 64;
    int* rcnt2 = sync + 68;
    int* scnt2 = sync + 132;

    dim3 rgrid(64, 16);

    // layer 1
    k_encproj<<<N / 8, 256, 0, stream>>>(x, W_enc, b_enc, W1, as1, ad1,
                                         h2, ssrc1, sdst1, sync);
    k_rank_f<<<rgrid, 256, 0, stream>>>(ssrc1, rpart, rcnt1, srtv, srti);
    k_s3off<<<256, 512, 0, stream>>>(h2, srti, srtv, TA, TB, scnt1, SA, PB, SufT, PreT);
    k_targetproj<<<N / 8, 256, 0, stream>>>(sdst1, srtv, SA, PB, SufT, PreT, b1,
                                            W2, as2, ad2, h2, ssrc2, sdst2);
    // layer 2
    k_rank_f<<<rgrid, 256, 0, stream>>>(ssrc2, rpart, rcnt2, srtv, srti);
    k_s3off<<<256, 512, 0, stream>>>(h2, srti, srtv, TA, TB, scnt2, SA, PB, SufT, PreT);
    k_target2<<<N / 4, 256, 0, stream>>>(sdst2, srtv, SA, PB, SufT, PreT, b2,
                                         W_act, b_act, W_cri, b_cri, out);
}